// Round 15
// baseline (147.162 us; speedup 1.0000x reference)
//
#include <hip/hip_runtime.h>

#define BB 2
#define TT 512
#define HH 256
#define NBT (BB * TT)          // 1024

#define C2LOG2E 2.8853900817779268f   // 2*log2(e): exp(2x)=2^(C*x)
#define LOG2E   1.4426950408889634f

typedef __attribute__((ext_vector_type(8))) short short8;
typedef __attribute__((ext_vector_type(4))) float f32x4;

__device__ __forceinline__ unsigned short f2bf(float f) {   // RNE float->bf16
    unsigned u = __float_as_uint(f);
    unsigned r = u + 0x7fffu + ((u >> 16) & 1u);
    return (unsigned short)(r >> 16);
}

// load 8 consecutive fp32 and convert to a bf16 MFMA fragment
__device__ __forceinline__ short8 load_cvt8(const float* __restrict__ p) {
    float4 x0 = *reinterpret_cast<const float4*>(p);
    float4 x1 = *reinterpret_cast<const float4*>(p + 4);
    short8 r;
    r[0] = (short)f2bf(x0.x); r[1] = (short)f2bf(x0.y);
    r[2] = (short)f2bf(x0.z); r[3] = (short)f2bf(x0.w);
    r[4] = (short)f2bf(x1.x); r[5] = (short)f2bf(x1.y);
    r[6] = (short)f2bf(x1.z); r[7] = (short)f2bf(x1.w);
    return r;
}

// ---------------------------------------------------------------------------
// Fused kernel, plain launch (graph-capture safe). Grid 1024 x 512.
// __launch_bounds__(512,8) -> <=64 VGPR -> 4 blocks/CU -> all 1024 resident.
// Phase 1: waves 0-1 of EVERY block each compute one 16x16 MFMA proj tile
//          (2048 tiles total, spread evenly over all 256 CUs).
// Software ticket barrier (device-scope atomics on ws counter, zeroed by a
// hipMemsetAsync node each launch -> replay-deterministic).
// Phase 2: proven attn structure (~5.8us): rcp-scores + sum-softmax + ctx.
// ---------------------------------------------------------------------------
__global__ __launch_bounds__(512, 8) void fused_kernel(
    const float* __restrict__ Q, const float* __restrict__ K,
    const float* __restrict__ Wq, const float* __restrict__ Wk,
    const float* __restrict__ v,
    float* __restrict__ ctx, float* __restrict__ alpha,
    float* __restrict__ Eq, float* __restrict__ EkT,
    unsigned* __restrict__ cnt)
{
    int tid = threadIdx.x;
    int bid = blockIdx.x;
    int wv = tid >> 6;

    // ================= Phase 1: projection (waves 0,1) =================
    if (wv < 2) {
        int tileid = bid * 2 + wv;             // 0..2047
        int lane = tid & 63;
        int btile = tileid >> 4;               // 0..127 (x16 bt-rows)
        int otile = tileid & 15;               // 0..15  (x16 outs)
        bool isK = (btile >= 64);
        int bt0 = (btile & 63) * 16;
        int o0 = otile * 16;
        const float* X = isK ? K : Q;
        const float* W = isK ? Wk : Wq;

        int rsel = lane & 15;
        int ksel = (lane >> 4) * 8;
        const float* xp = X + (bt0 + rsel) * HH + ksel;
        const float* wp = W + (o0 + rsel) * HH + ksel;

        f32x4 acc = {0.f, 0.f, 0.f, 0.f};
#pragma unroll 2
        for (int kb = 0; kb < 8; ++kb) {
            short8 a = load_cvt8(xp + kb * 32);
            short8 b = load_cvt8(wp + kb * 32);
            acc = __builtin_amdgcn_mfma_f32_16x16x32_bf16(a, b, acc, 0, 0, 0);
        }

        int rbase = bt0 + (lane >> 4) * 4;     // C/D row base (bt index)
        int o = o0 + (lane & 15);              // out channel
#pragma unroll
        for (int j = 0; j < 4; ++j) {
            float e = __builtin_amdgcn_exp2f(acc[j] * C2LOG2E);
            int r = rbase + j;
            if (!isK)
                Eq[r * HH + o] = e;
            else
                EkT[((o >> 2) * NBT + r) * 4 + (o & 3)] = e;
        }
    }

    // ================= software grid barrier =================
    __syncthreads();                           // block's proj writes issued
    if (tid == 0) {
        __threadfence();                       // release: publish Eq/EkT
        atomicAdd(cnt, 1u);
        while (atomicAdd(cnt, 0u) < (unsigned)NBT) {
            __builtin_amdgcn_s_sleep(2);
        }
        __threadfence();                       // acquire
    }
    __syncthreads();

    // ================= Phase 2: attention =================
    __shared__ float eq_sh[HH];
    __shared__ float v2_sh[HH];
    __shared__ float al_sh[TT];
    __shared__ float red[8];
    __shared__ float4 cred[8][64];

    int bt = bid;
    int b = bt / TT;
    int idx = bt % TT;
    int t = (idx < 256) ? idx : 767 - idx;     // bijective load-balance
    int btr = b * TT + t;

    if (tid < HH) {
        eq_sh[tid] = Eq[btr * HH + tid];
        v2_sh[tid] = -2.0f * v[tid];
    }
    __syncthreads();

    // ---- score for s = tid (coalesced EkT loads: lanes contiguous) ----
    float sc = 0.f;
    if (tid <= t) {
        const float4* ek = reinterpret_cast<const float4*>(EkT) + (b * TT + tid);
        const float4* q4p = reinterpret_cast<const float4*>(eq_sh);
        const float4* v4p = reinterpret_cast<const float4*>(v2_sh);
#pragma unroll 4
        for (int h4 = 0; h4 < HH / 4; ++h4) {
            float4 e4 = ek[h4 * NBT];     // 1KB/wave
            float4 q4 = q4p[h4];          // broadcast
            float4 vv = v4p[h4];          // broadcast
            float r0 = __builtin_amdgcn_rcpf(__builtin_fmaf(q4.x, e4.x, 1.f));
            float r1 = __builtin_amdgcn_rcpf(__builtin_fmaf(q4.y, e4.y, 1.f));
            float r2 = __builtin_amdgcn_rcpf(__builtin_fmaf(q4.z, e4.z, 1.f));
            float r3 = __builtin_amdgcn_rcpf(__builtin_fmaf(q4.w, e4.w, 1.f));
            sc = __builtin_fmaf(vv.x, r0, sc);
            sc = __builtin_fmaf(vv.y, r1, sc);
            sc = __builtin_fmaf(vv.z, r2, sc);
            sc = __builtin_fmaf(vv.w, r3, sc);
        }
    }

    // ---- softmax: sum only (scores bounded by 2*sum|v| ~ 26) ----
    float e = (tid <= t) ? __builtin_amdgcn_exp2f(sc * LOG2E) : 0.f;
    float ssum = e;
#pragma unroll
    for (int off = 32; off > 0; off >>= 1)
        ssum += __shfl_xor(ssum, off);
    if ((tid & 63) == 0) red[tid >> 6] = ssum;
    __syncthreads();
    float denom = (red[0] + red[1]) + (red[2] + red[3])
                + (red[4] + red[5]) + (red[6] + red[7]);
    float a0 = e * __builtin_amdgcn_rcpf(denom);

    al_sh[tid] = a0;
    alpha[btr * TT + tid] = a0;
    __syncthreads();

    // ---- context: hc = tid&63 (4 channels), sg = tid>>6 (s-stride 8) ----
    int hc = tid & 63, sg = tid >> 6;
    const float4* kb4 = reinterpret_cast<const float4*>(K + b * TT * HH) + hc;
    float4 acc4 = {0.f, 0.f, 0.f, 0.f};
    for (int s = sg; s <= t; s += 8) {
        float4 k4 = kb4[s * 64];             // coalesced 1KB/wave
        float  al = al_sh[s];                // wave-uniform broadcast
        acc4.x = __builtin_fmaf(al, k4.x, acc4.x);
        acc4.y = __builtin_fmaf(al, k4.y, acc4.y);
        acc4.z = __builtin_fmaf(al, k4.z, acc4.z);
        acc4.w = __builtin_fmaf(al, k4.w, acc4.w);
    }
    cred[sg][hc] = acc4;
    __syncthreads();
    if (sg == 0) {
        float4 out = {0.f, 0.f, 0.f, 0.f};
#pragma unroll
        for (int g = 0; g < 8; ++g) {
            float4 cc = cred[g][hc];
            out.x += cc.x; out.y += cc.y; out.z += cc.z; out.w += cc.w;
        }
        reinterpret_cast<float4*>(ctx + btr * HH)[hc] = out;
    }
}

extern "C" void kernel_launch(void* const* d_in, const int* in_sizes, int n_in,
                              void* d_out, int out_size, void* d_ws, size_t ws_size,
                              hipStream_t stream) {
    const float* Q  = (const float*)d_in[0];
    const float* K  = (const float*)d_in[1];
    const float* Wq = (const float*)d_in[2];
    const float* Wk = (const float*)d_in[3];
    const float* v  = (const float*)d_in[4];

    float* ctx   = (float*)d_out;                      // B*T*H
    float* alpha = (float*)d_out + NBT * HH;           // B*T*T

    float* Eq  = (float*)d_ws;                         // NBT*HH fp32 (1 MB)
    float* EkT = Eq + NBT * HH;                        // NBT*HH fp32 (1 MB)
    unsigned* cnt = (unsigned*)(EkT + NBT * HH);       // barrier counter

    hipMemsetAsync((void*)cnt, 0, 4, stream);          // capture-legal memset node
    fused_kernel<<<NBT, 512, 0, stream>>>(Q, K, Wq, Wk, v,
                                          ctx, alpha, Eq, EkT, cnt);
}

// Round 16
// 80.218 us; speedup vs baseline: 1.8345x; 1.8345x over previous
//
#include <hip/hip_runtime.h>

#define BB 2
#define TT 512
#define HH 256
#define NBT (BB * TT)          // 1024

#define C2LOG2E 2.8853900817779268f   // 2*log2(e): exp(2x)=2^(C*x)
#define LOG2E   1.4426950408889634f

typedef __attribute__((ext_vector_type(8))) short short8;
typedef __attribute__((ext_vector_type(4))) float f32x4;

__device__ __forceinline__ unsigned short f2bf(float f) {   // RNE float->bf16
    unsigned u = __float_as_uint(f);
    unsigned r = u + 0x7fffu + ((u >> 16) & 1u);
    return (unsigned short)(r >> 16);
}

// load 8 consecutive fp32 and convert to a bf16 MFMA fragment
__device__ __forceinline__ short8 load_cvt8(const float* __restrict__ p) {
    float4 x0 = *reinterpret_cast<const float4*>(p);
    float4 x1 = *reinterpret_cast<const float4*>(p + 4);
    short8 r;
    r[0] = (short)f2bf(x0.x); r[1] = (short)f2bf(x0.y);
    r[2] = (short)f2bf(x0.z); r[3] = (short)f2bf(x0.w);
    r[4] = (short)f2bf(x1.x); r[5] = (short)f2bf(x1.y);
    r[6] = (short)f2bf(x1.z); r[7] = (short)f2bf(x1.w);
    return r;
}

// ---------------------------------------------------------------------------
// Fused kernel, plain launch (graph-capture safe; structure proven in R15).
// Grid 1024 x 512, __launch_bounds__(512,8) -> all blocks co-resident.
// Phase 1: blocks 0..127 are producers; each computes 16 MFMA proj tiles
//          (2 per wave, all 8 waves busy) -> Eq / EkT in ws.
// Barrier: 128 atomic arrivals; everyone polls with a relaxed atomic LOAD
//          (no RMW contention) + s_sleep backoff.
// Phase 2: proven attn structure: rcp-scores + sum-softmax + ctx.
// ---------------------------------------------------------------------------
__global__ __launch_bounds__(512, 8) void fused_kernel(
    const float* __restrict__ Q, const float* __restrict__ K,
    const float* __restrict__ Wq, const float* __restrict__ Wk,
    const float* __restrict__ v,
    float* __restrict__ ctx, float* __restrict__ alpha,
    float* __restrict__ Eq, float* __restrict__ EkT,
    unsigned* __restrict__ cnt)
{
    int tid = threadIdx.x;
    int bid = blockIdx.x;
    int wv = tid >> 6;
    int lane = tid & 63;

    // ================= Phase 1: projection (producer blocks) ============
    if (bid < 128) {
#pragma unroll
        for (int i = 0; i < 2; ++i) {
            int tileid = bid * 16 + wv * 2 + i;    // 0..2047
            int btile = tileid >> 4;               // 0..127 (x16 bt-rows)
            int otile = tileid & 15;               // 0..15  (x16 outs)
            bool isK = (btile >= 64);
            int bt0 = (btile & 63) * 16;
            int o0 = otile * 16;
            const float* X = isK ? K : Q;
            const float* W = isK ? Wk : Wq;

            int rsel = lane & 15;
            int ksel = (lane >> 4) * 8;
            const float* xp = X + (bt0 + rsel) * HH + ksel;
            const float* wp = W + (o0 + rsel) * HH + ksel;

            f32x4 acc = {0.f, 0.f, 0.f, 0.f};
#pragma unroll 2
            for (int kb = 0; kb < 8; ++kb) {
                short8 a = load_cvt8(xp + kb * 32);
                short8 b = load_cvt8(wp + kb * 32);
                acc = __builtin_amdgcn_mfma_f32_16x16x32_bf16(a, b, acc, 0, 0, 0);
            }

            int rbase = bt0 + (lane >> 4) * 4;     // C/D row base (bt index)
            int o = o0 + (lane & 15);              // out channel
#pragma unroll
            for (int j = 0; j < 4; ++j) {
                float e = __builtin_amdgcn_exp2f(acc[j] * C2LOG2E);
                int r = rbase + j;
                if (!isK)
                    Eq[r * HH + o] = e;
                else
                    EkT[((o >> 2) * NBT + r) * 4 + (o & 3)] = e;
            }
        }
        __syncthreads();                           // block's proj writes issued
        if (tid == 0) {
            __threadfence();                       // release: publish Eq/EkT
            atomicAdd(cnt, 1u);
        }
    }

    // ================= software grid barrier (load-poll) ================
    if (tid == 0) {
        while (__hip_atomic_load(cnt, __ATOMIC_RELAXED,
                                 __HIP_MEMORY_SCOPE_AGENT) < 128u)
            __builtin_amdgcn_s_sleep(8);
        __threadfence();                           // acquire
    }
    __syncthreads();

    // ================= Phase 2: attention =================
    __shared__ float eq_sh[HH];
    __shared__ float v2_sh[HH];
    __shared__ float al_sh[TT];
    __shared__ float red[8];
    __shared__ float4 cred[8][64];

    int bt = bid;
    int b = bt / TT;
    int idx = bt % TT;
    int t = (idx < 256) ? idx : 767 - idx;         // bijective load-balance
    int btr = b * TT + t;

    if (tid < HH) {
        eq_sh[tid] = Eq[btr * HH + tid];
        v2_sh[tid] = -2.0f * v[tid];
    }
    __syncthreads();

    // ---- score for s = tid (coalesced EkT loads: lanes contiguous) ----
    float sc = 0.f;
    if (tid <= t) {
        const float4* ek = reinterpret_cast<const float4*>(EkT) + (b * TT + tid);
        const float4* q4p = reinterpret_cast<const float4*>(eq_sh);
        const float4* v4p = reinterpret_cast<const float4*>(v2_sh);
#pragma unroll 4
        for (int h4 = 0; h4 < HH / 4; ++h4) {
            float4 e4 = ek[h4 * NBT];     // 1KB/wave
            float4 q4 = q4p[h4];          // broadcast
            float4 vv = v4p[h4];          // broadcast
            float r0 = __builtin_amdgcn_rcpf(__builtin_fmaf(q4.x, e4.x, 1.f));
            float r1 = __builtin_amdgcn_rcpf(__builtin_fmaf(q4.y, e4.y, 1.f));
            float r2 = __builtin_amdgcn_rcpf(__builtin_fmaf(q4.z, e4.z, 1.f));
            float r3 = __builtin_amdgcn_rcpf(__builtin_fmaf(q4.w, e4.w, 1.f));
            sc = __builtin_fmaf(vv.x, r0, sc);
            sc = __builtin_fmaf(vv.y, r1, sc);
            sc = __builtin_fmaf(vv.z, r2, sc);
            sc = __builtin_fmaf(vv.w, r3, sc);
        }
    }

    // ---- softmax: sum only (scores bounded by 2*sum|v| ~ 26) ----
    float e = (tid <= t) ? __builtin_amdgcn_exp2f(sc * LOG2E) : 0.f;
    float ssum = e;
#pragma unroll
    for (int off = 32; off > 0; off >>= 1)
        ssum += __shfl_xor(ssum, off);
    if ((tid & 63) == 0) red[tid >> 6] = ssum;
    __syncthreads();
    float denom = (red[0] + red[1]) + (red[2] + red[3])
                + (red[4] + red[5]) + (red[6] + red[7]);
    float a0 = e * __builtin_amdgcn_rcpf(denom);

    al_sh[tid] = a0;
    alpha[btr * TT + tid] = a0;
    __syncthreads();

    // ---- context: hc = tid&63 (4 channels), sg = tid>>6 (s-stride 8) ----
    int hc = tid & 63, sg = tid >> 6;
    const float4* kb4 = reinterpret_cast<const float4*>(K + b * TT * HH) + hc;
    float4 acc4 = {0.f, 0.f, 0.f, 0.f};
    for (int s = sg; s <= t; s += 8) {
        float4 k4 = kb4[s * 64];             // coalesced 1KB/wave
        float  al = al_sh[s];                // wave-uniform broadcast
        acc4.x = __builtin_fmaf(al, k4.x, acc4.x);
        acc4.y = __builtin_fmaf(al, k4.y, acc4.y);
        acc4.z = __builtin_fmaf(al, k4.z, acc4.z);
        acc4.w = __builtin_fmaf(al, k4.w, acc4.w);
    }
    cred[sg][hc] = acc4;
    __syncthreads();
    if (sg == 0) {
        float4 out = {0.f, 0.f, 0.f, 0.f};
#pragma unroll
        for (int g = 0; g < 8; ++g) {
            float4 cc = cred[g][hc];
            out.x += cc.x; out.y += cc.y; out.z += cc.z; out.w += cc.w;
        }
        reinterpret_cast<float4*>(ctx + btr * HH)[hc] = out;
    }
}

extern "C" void kernel_launch(void* const* d_in, const int* in_sizes, int n_in,
                              void* d_out, int out_size, void* d_ws, size_t ws_size,
                              hipStream_t stream) {
    const float* Q  = (const float*)d_in[0];
    const float* K  = (const float*)d_in[1];
    const float* Wq = (const float*)d_in[2];
    const float* Wk = (const float*)d_in[3];
    const float* v  = (const float*)d_in[4];

    float* ctx   = (float*)d_out;                      // B*T*H
    float* alpha = (float*)d_out + NBT * HH;           // B*T*T

    float* Eq  = (float*)d_ws;                         // NBT*HH fp32 (1 MB)
    float* EkT = Eq + NBT * HH;                        // NBT*HH fp32 (1 MB)
    unsigned* cnt = (unsigned*)(EkT + NBT * HH);       // barrier counter

    hipMemsetAsync((void*)cnt, 0, 4, stream);          // capture-legal memset node
    fused_kernel<<<NBT, 512, 0, stream>>>(Q, K, Wq, Wk, v,
                                          ctx, alpha, Eq, EkT, cnt);
}

// Round 17
// 42.983 us; speedup vs baseline: 3.4237x; 1.8663x over previous
//
#include <hip/hip_runtime.h>

#define BB 2
#define TT 512
#define HH 256
#define NBT (BB * TT)          // 1024

#define C2LOG2E 2.8853900817779268f   // 2*log2(e): exp(2x)=2^(C*x)
#define LOG2E   1.4426950408889634f

// ---------------------------------------------------------------------------
// Kernel 1 (proj): EXACT round-3 structure (measured 9.3us in round-4 bench).
// Grid 256 x 256thr (1 block/CU). 8 rows/block, thread = output channel o.
// X loads wave-uniform f4; W row-major per-thread f4 (scatter is fine at
// 1 block/CU per the segment model); writes row-major coalesced.
// Y[bt,o] = exp2(C * sum_h X[bt,h]*W[o,h])
// ---------------------------------------------------------------------------
__global__ __launch_bounds__(256) void proj_kernel(
    const float* __restrict__ Q, const float* __restrict__ K,
    const float* __restrict__ Wq, const float* __restrict__ Wk,
    float* __restrict__ Eq, float* __restrict__ Ek)
{
    const int ROWS = 8;
    int grp = blockIdx.x;
    const int nQ = (BB * TT) / ROWS;          // 128
    bool isK = (grp >= nQ);
    int bt0 = (isK ? grp - nQ : grp) * ROWS;
    const float* X = isK ? K : Q;
    const float* W = isK ? Wk : Wq;
    float* Y = isK ? Ek : Eq;

    int o = threadIdx.x;
    const float4* w4p = reinterpret_cast<const float4*>(W + o * HH);
    const float4* x4p = reinterpret_cast<const float4*>(X + bt0 * HH);

    float acc[ROWS] = {0.f, 0.f, 0.f, 0.f, 0.f, 0.f, 0.f, 0.f};
#pragma unroll 2
    for (int h4 = 0; h4 < HH / 4; ++h4) {
        float4 w4 = w4p[h4];
#pragma unroll
        for (int r = 0; r < ROWS; ++r) {
            float4 x4 = x4p[r * (HH / 4) + h4];   // wave-uniform address
            acc[r] += x4.x * w4.x + x4.y * w4.y + x4.z * w4.z + x4.w * w4.w;
        }
    }
#pragma unroll
    for (int r = 0; r < ROWS; ++r)
        Y[(bt0 + r) * HH + o] = __builtin_amdgcn_exp2f(acc[r] * C2LOG2E);
}

// ---------------------------------------------------------------------------
// Kernel 2 (trans): Ek [1024][256] row-major -> EkT f4-slab layout
// EkT[(h4*NBT + bt)*4 + c] = Ek[bt][h4*4+c], via 64x64 LDS tiles.
// Grid 64 (16 bt-tiles x 4 h-tiles), 256 thr. All global ops coalesced.
// ---------------------------------------------------------------------------
__global__ __launch_bounds__(256) void trans_kernel(
    const float* __restrict__ Ek, float* __restrict__ EkT)
{
    __shared__ float t_sh[64][65];
    int bid = blockIdx.x;
    int bt0 = (bid & 15) * 64;
    int h0  = (bid >> 4) * 64;
    int tid = threadIdx.x;
    int ty = tid >> 6, tx = tid & 63;

#pragma unroll
    for (int p = 0; p < 16; ++p) {
        int rr = p * 4 + ty;                       // bt row within tile
        t_sh[tx][rr] = Ek[(bt0 + rr) * HH + h0 + tx];   // 256B/wave coalesced
    }
    __syncthreads();
#pragma unroll
    for (int p = 0; p < 4; ++p) {
        int s = p * 4 + ty;                        // local h4 0..15
        float4 val;
        val.x = t_sh[s * 4 + 0][tx];
        val.y = t_sh[s * 4 + 1][tx];
        val.z = t_sh[s * 4 + 2][tx];
        val.w = t_sh[s * 4 + 3][tx];
        *reinterpret_cast<float4*>(
            EkT + (((h0 >> 2) + s) * NBT + bt0 + tx) * 4) = val;  // 1KB/wave
    }
}

// ---------------------------------------------------------------------------
// Kernel 3 (attn): proven 5.8us structure, verbatim.
// scores via rcp(Eq*Ek+1) + sum-only softmax + fp32 K context.
// ---------------------------------------------------------------------------
__global__ __launch_bounds__(512, 8) void attn_kernel(
    const float* __restrict__ Eq, const float* __restrict__ EkT,
    const float* __restrict__ Kraw, const float* __restrict__ v,
    float* __restrict__ ctx, float* __restrict__ alpha)
{
    __shared__ float eq_sh[HH];
    __shared__ float v2_sh[HH];
    __shared__ float al_sh[TT];
    __shared__ float red[8];
    __shared__ float4 cred[8][64];

    int bt = blockIdx.x;
    int b = bt / TT;
    int idx = bt % TT;
    int t = (idx < 256) ? idx : 767 - idx;
    int btr = b * TT + t;
    int tid = threadIdx.x;

    if (tid < HH) {
        eq_sh[tid] = Eq[btr * HH + tid];
        v2_sh[tid] = -2.0f * v[tid];
    }
    __syncthreads();

    // ---- score for s = tid (coalesced EkT loads: lanes contiguous) ----
    float sc = 0.f;
    if (tid <= t) {
        const float4* ek = reinterpret_cast<const float4*>(EkT) + (b * TT + tid);
        const float4* q4p = reinterpret_cast<const float4*>(eq_sh);
        const float4* v4p = reinterpret_cast<const float4*>(v2_sh);
#pragma unroll 4
        for (int h4 = 0; h4 < HH / 4; ++h4) {
            float4 e4 = ek[h4 * NBT];     // 1KB/wave
            float4 q4 = q4p[h4];          // broadcast
            float4 vv = v4p[h4];          // broadcast
            float r0 = __builtin_amdgcn_rcpf(__builtin_fmaf(q4.x, e4.x, 1.f));
            float r1 = __builtin_amdgcn_rcpf(__builtin_fmaf(q4.y, e4.y, 1.f));
            float r2 = __builtin_amdgcn_rcpf(__builtin_fmaf(q4.z, e4.z, 1.f));
            float r3 = __builtin_amdgcn_rcpf(__builtin_fmaf(q4.w, e4.w, 1.f));
            sc = __builtin_fmaf(vv.x, r0, sc);
            sc = __builtin_fmaf(vv.y, r1, sc);
            sc = __builtin_fmaf(vv.z, r2, sc);
            sc = __builtin_fmaf(vv.w, r3, sc);
        }
    }

    // ---- softmax: sum only (scores bounded by 2*sum|v| ~ 26) ----
    float e = (tid <= t) ? __builtin_amdgcn_exp2f(sc * LOG2E) : 0.f;
    float ssum = e;
#pragma unroll
    for (int off = 32; off > 0; off >>= 1)
        ssum += __shfl_xor(ssum, off);
    if ((tid & 63) == 0) red[tid >> 6] = ssum;
    __syncthreads();
    float denom = (red[0] + red[1]) + (red[2] + red[3])
                + (red[4] + red[5]) + (red[6] + red[7]);
    float a0 = e * __builtin_amdgcn_rcpf(denom);

    al_sh[tid] = a0;
    alpha[btr * TT + tid] = a0;
    __syncthreads();

    // ---- context: hc = tid&63 (4 channels), sg = tid>>6 (s-stride 8) ----
    int hc = tid & 63, sg = tid >> 6;
    const float4* kb4 = reinterpret_cast<const float4*>(Kraw + b * TT * HH) + hc;
    float4 acc4 = {0.f, 0.f, 0.f, 0.f};
    for (int s = sg; s <= t; s += 8) {
        float4 k4 = kb4[s * 64];             // coalesced 1KB/wave
        float  al = al_sh[s];                // wave-uniform broadcast
        acc4.x = __builtin_fmaf(al, k4.x, acc4.x);
        acc4.y = __builtin_fmaf(al, k4.y, acc4.y);
        acc4.z = __builtin_fmaf(al, k4.z, acc4.z);
        acc4.w = __builtin_fmaf(al, k4.w, acc4.w);
    }
    cred[sg][hc] = acc4;
    __syncthreads();
    if (sg == 0) {
        float4 out = {0.f, 0.f, 0.f, 0.f};
#pragma unroll
        for (int g = 0; g < 8; ++g) {
            float4 cc = cred[g][hc];
            out.x += cc.x; out.y += cc.y; out.z += cc.z; out.w += cc.w;
        }
        reinterpret_cast<float4*>(ctx + btr * HH)[hc] = out;
    }
}

extern "C" void kernel_launch(void* const* d_in, const int* in_sizes, int n_in,
                              void* d_out, int out_size, void* d_ws, size_t ws_size,
                              hipStream_t stream) {
    const float* Q  = (const float*)d_in[0];
    const float* K  = (const float*)d_in[1];
    const float* Wq = (const float*)d_in[2];
    const float* Wk = (const float*)d_in[3];
    const float* v  = (const float*)d_in[4];

    float* ctx   = (float*)d_out;                      // B*T*H
    float* alpha = (float*)d_out + NBT * HH;           // B*T*T

    // ws: Eq | Ek | EkT  (fp32, 3 MB)
    float* Eq  = (float*)d_ws;                         // NBT*HH
    float* Ek  = Eq + NBT * HH;                        // NBT*HH (row-major)
    float* EkT = Ek + NBT * HH;                        // NBT*HH (f4-slab)

    proj_kernel<<<256, 256, 0, stream>>>(Q, K, Wq, Wk, Eq, Ek);
    trans_kernel<<<64, 256, 0, stream>>>(Ek, EkT);
    attn_kernel<<<NBT, 512, 0, stream>>>(Eq, EkT, K, v, ctx, alpha);
}

// Round 18
// 38.442 us; speedup vs baseline: 3.8282x; 1.1181x over previous
//
#include <hip/hip_runtime.h>

#define BB 2
#define TT 512
#define HH 256
#define NBT (BB * TT)          // 1024

#define C2LOG2E 2.8853900817779268f   // 2*log2(e): exp(2x)=2^(C*x)
#define LOG2E   1.4426950408889634f

typedef __attribute__((ext_vector_type(8))) short short8;
typedef __attribute__((ext_vector_type(4))) float f32x4;

__device__ __forceinline__ unsigned short f2bf(float f) {   // RNE float->bf16
    unsigned u = __float_as_uint(f);
    unsigned r = u + 0x7fffu + ((u >> 16) & 1u);
    return (unsigned short)(r >> 16);
}

// load 8 consecutive fp32 and convert to a bf16 MFMA fragment
__device__ __forceinline__ short8 load_cvt8(const float* __restrict__ p) {
    float4 x0 = *reinterpret_cast<const float4*>(p);
    float4 x1 = *reinterpret_cast<const float4*>(p + 4);
    short8 r;
    r[0] = (short)f2bf(x0.x); r[1] = (short)f2bf(x0.y);
    r[2] = (short)f2bf(x0.z); r[3] = (short)f2bf(x0.w);
    r[4] = (short)f2bf(x1.x); r[5] = (short)f2bf(x1.y);
    r[6] = (short)f2bf(x1.z); r[7] = (short)f2bf(x1.w);
    return r;
}

// ---------------------------------------------------------------------------
// Kernel 1 (proj_mfma): R11 structure (best measured total, 37.5us), with
// the EkT epilogue's 4B-per-lane scatter replaced by a wave-private LDS
// bounce -> 256B-contiguous float4 runs (16 lanes x consecutive bt-rows).
// One 16x16 tile/wave, 2048 waves (grid 512 x 256thr).
// A-frag lane l: X[bt0 + (l&15)][kb*32 + (l>>4)*8 + j]
// B-frag lane l: W[o0  + (l&15)][kb*32 + (l>>4)*8 + j]   (B = W^T)
// C/D lane l reg j: row = (l>>4)*4 + j, col = l&15   [m89-verified]
// ---------------------------------------------------------------------------
__global__ __launch_bounds__(256) void proj_mfma_kernel(
    const float* __restrict__ Q, const float* __restrict__ K,
    const float* __restrict__ Wq, const float* __restrict__ Wk,
    float* __restrict__ Eq, float* __restrict__ EkT)
{
    __shared__ float bounce[4][16][17];        // per-wave 16x16 tile, pad 17

    int wv = threadIdx.x >> 6;
    int wid_g = blockIdx.x * 4 + wv;           // 0..2047
    int lane = threadIdx.x & 63;
    int btile = wid_g >> 4;                    // 0..127  (x16 rows)
    int otile = wid_g & 15;                    // 0..15   (x16 outs)
    bool isK = (btile >= 64);
    int bt0 = (btile & 63) * 16;
    int o0 = otile * 16;
    const float* X = isK ? K : Q;
    const float* W = isK ? Wk : Wq;

    int rsel = lane & 15;                      // row-within-16 for A/B frags
    int ksel = (lane >> 4) * 8;                // k-offset within 32

    const float* xp = X + (bt0 + rsel) * HH + ksel;
    const float* wp = W + (o0 + rsel) * HH + ksel;

    f32x4 acc = {0.f, 0.f, 0.f, 0.f};
#pragma unroll 2
    for (int kb = 0; kb < 8; ++kb) {
        short8 a = load_cvt8(xp + kb * 32);
        short8 b = load_cvt8(wp + kb * 32);
        acc = __builtin_amdgcn_mfma_f32_16x16x32_bf16(a, b, acc, 0, 0, 0);
    }

    int rloc = (lane >> 4) * 4;                // C/D local row base
    int cloc = lane & 15;                      // C/D local col
    if (!isK) {
        int o = o0 + cloc;
#pragma unroll
        for (int j = 0; j < 4; ++j) {
            float e = __builtin_amdgcn_exp2f(acc[j] * C2LOG2E);
            Eq[(bt0 + rloc + j) * HH + o] = e;     // 4 x 64B segs/instr
        }
    } else {
        // stage tile in wave-private LDS (no barrier: same-wave readback)
#pragma unroll
        for (int j = 0; j < 4; ++j)
            bounce[wv][rloc + j][cloc] =
                __builtin_amdgcn_exp2f(acc[j] * C2LOG2E);
        // lanes 0-15: oq=0 rows 0-15; 16-31: oq=1; ... -> each 16-lane
        // group writes 16 consecutive (bt,4-out) f4 slots = 256B contiguous
        int oq = lane >> 4;                    // out-quad 0..3
        int r  = lane & 15;                    // bt row 0..15
        float4 val;
        val.x = bounce[wv][r][oq * 4 + 0];
        val.y = bounce[wv][r][oq * 4 + 1];
        val.z = bounce[wv][r][oq * 4 + 2];
        val.w = bounce[wv][r][oq * 4 + 3];
        *reinterpret_cast<float4*>(
            EkT + (((o0 >> 2) + oq) * NBT + bt0 + r) * 4) = val;
    }
}

// ---------------------------------------------------------------------------
// Kernel 2 (attn): proven structure, verbatim (R11).
// scores via rcp(Eq*Ek+1) + sum-only softmax + fp32 K context.
// ---------------------------------------------------------------------------
__global__ __launch_bounds__(512, 8) void attn_kernel(
    const float* __restrict__ Eq, const float* __restrict__ EkT,
    const float* __restrict__ Kraw, const float* __restrict__ v,
    float* __restrict__ ctx, float* __restrict__ alpha)
{
    __shared__ float eq_sh[HH];
    __shared__ float v2_sh[HH];
    __shared__ float al_sh[TT];
    __shared__ float red[8];
    __shared__ float4 cred[8][64];

    int bt = blockIdx.x;
    int b = bt / TT;
    int idx = bt % TT;
    int t = (idx < 256) ? idx : 767 - idx;
    int btr = b * TT + t;
    int tid = threadIdx.x;

    if (tid < HH) {
        eq_sh[tid] = Eq[btr * HH + tid];
        v2_sh[tid] = -2.0f * v[tid];
    }
    __syncthreads();

    // ---- score for s = tid (coalesced EkT loads: lanes contiguous) ----
    float sc = 0.f;
    if (tid <= t) {
        const float4* ek = reinterpret_cast<const float4*>(EkT) + (b * TT + tid);
        const float4* q4p = reinterpret_cast<const float4*>(eq_sh);
        const float4* v4p = reinterpret_cast<const float4*>(v2_sh);
#pragma unroll 4
        for (int h4 = 0; h4 < HH / 4; ++h4) {
            float4 e4 = ek[h4 * NBT];     // 1KB/wave
            float4 q4 = q4p[h4];          // broadcast
            float4 vv = v4p[h4];          // broadcast
            float r0 = __builtin_amdgcn_rcpf(__builtin_fmaf(q4.x, e4.x, 1.f));
            float r1 = __builtin_amdgcn_rcpf(__builtin_fmaf(q4.y, e4.y, 1.f));
            float r2 = __builtin_amdgcn_rcpf(__builtin_fmaf(q4.z, e4.z, 1.f));
            float r3 = __builtin_amdgcn_rcpf(__builtin_fmaf(q4.w, e4.w, 1.f));
            sc = __builtin_fmaf(vv.x, r0, sc);
            sc = __builtin_fmaf(vv.y, r1, sc);
            sc = __builtin_fmaf(vv.z, r2, sc);
            sc = __builtin_fmaf(vv.w, r3, sc);
        }
    }

    // ---- softmax: sum only (scores bounded by 2*sum|v| ~ 26) ----
    float e = (tid <= t) ? __builtin_amdgcn_exp2f(sc * LOG2E) : 0.f;
    float ssum = e;
#pragma unroll
    for (int off = 32; off > 0; off >>= 1)
        ssum += __shfl_xor(ssum, off);
    if ((tid & 63) == 0) red[tid >> 6] = ssum;
    __syncthreads();
    float denom = (red[0] + red[1]) + (red[2] + red[3])
                + (red[4] + red[5]) + (red[6] + red[7]);
    float a0 = e * __builtin_amdgcn_rcpf(denom);

    al_sh[tid] = a0;
    alpha[btr * TT + tid] = a0;
    __syncthreads();

    // ---- context: hc = tid&63 (4 channels), sg = tid>>6 (s-stride 8) ----
    int hc = tid & 63, sg = tid >> 6;
    const float4* kb4 = reinterpret_cast<const float4*>(Kraw + b * TT * HH) + hc;
    float4 acc4 = {0.f, 0.f, 0.f, 0.f};
    for (int s = sg; s <= t; s += 8) {
        float4 k4 = kb4[s * 64];             // coalesced 1KB/wave
        float  al = al_sh[s];                // wave-uniform broadcast
        acc4.x = __builtin_fmaf(al, k4.x, acc4.x);
        acc4.y = __builtin_fmaf(al, k4.y, acc4.y);
        acc4.z = __builtin_fmaf(al, k4.z, acc4.z);
        acc4.w = __builtin_fmaf(al, k4.w, acc4.w);
    }
    cred[sg][hc] = acc4;
    __syncthreads();
    if (sg == 0) {
        float4 out = {0.f, 0.f, 0.f, 0.f};
#pragma unroll
        for (int g = 0; g < 8; ++g) {
            float4 cc = cred[g][hc];
            out.x += cc.x; out.y += cc.y; out.z += cc.z; out.w += cc.w;
        }
        reinterpret_cast<float4*>(ctx + btr * HH)[hc] = out;
    }
}

extern "C" void kernel_launch(void* const* d_in, const int* in_sizes, int n_in,
                              void* d_out, int out_size, void* d_ws, size_t ws_size,
                              hipStream_t stream) {
    const float* Q  = (const float*)d_in[0];
    const float* K  = (const float*)d_in[1];
    const float* Wq = (const float*)d_in[2];
    const float* Wk = (const float*)d_in[3];
    const float* v  = (const float*)d_in[4];

    float* ctx   = (float*)d_out;                      // B*T*H
    float* alpha = (float*)d_out + NBT * HH;           // B*T*T

    // ws: Eq fp32 | EkT fp32
    float* Eq  = (float*)d_ws;                         // NBT*HH (1 MB)
    float* EkT = Eq + NBT * HH;                        // NBT*HH (1 MB)

    proj_mfma_kernel<<<512, 256, 0, stream>>>(Q, K, Wq, Wk, Eq, EkT);
    attn_kernel<<<NBT, 512, 0, stream>>>(Eq, EkT, K, v, ctx, alpha);
}